// Round 1
// baseline (371.000 us; speedup 1.0000x reference)
//
#include <hip/hip_runtime.h>
#include <math.h>

// ---------------- problem constants (from setup_inputs) ----------------
#define NB 4
#define NH 96
#define NW 96
#define ND 768
#define NPIX (NH*NW)          // 9216
#define RR 3
#define NK 49
#define TILE 16
#define HALO (TILE + 2*RR)    // 22
#define NVIS (HALO*HALO)      // 484
#define DC 16                 // D-chunk staged in LDS per iteration
#define LDST 20               // padded LDS stride (16B-aligned, conflict-reducing)
#define TAU 0.1f
#define SCALE 0.03608439182435161f  // 1/sqrt(768)
#define UNI (1.0f/49.0f)

// ws float layout:
//   part : [ns][b][51][NPIX]  (49 raw corr, 49: rubin_ss, 50: vis_ss)
//   invr : [b][NPIX]
//   invv : [b][NPIX]
//   dyl  : [b][NPIX]
//   dxl  : [b][NPIX]
//   gacc : [b][49][144]       per-wave partial sums of t=logits/TAU
//   gres : dyg[4], dxg[4]
// out float layout (flat concat, return order):
//   dra[36864] | ddec[36864] | conf_local[36864] | conf_global[4] | lw[36864]

// ---------------- kernel B: raw correlations + sums of squares ----------------
__global__ __launch_bounds__(256, 2) void corr_kernel(
    const float* __restrict__ rubin, const float* __restrict__ vis,
    float* __restrict__ part, int DQ) {
  __shared__ float lds[NVIS * LDST];   // 38,720 B
  const int tid = threadIdx.x;
  const int tileX = blockIdx.x % 6, tileY = blockIdx.x / 6;
  const int ns = blockIdx.y, b = blockIdx.z;
  const int tx = tid & 15, ty = tid >> 4;
  const int h = tileY*TILE + ty, w = tileX*TILE + tx;
  const int d0 = ns * DQ;
  const int nch = DQ / DC;

  // vis pixels this thread stages (edge-clamped = 'edge' padding)
  const int vp0 = tid, vp1 = tid + 256;
  const int vy0 = vp0 / HALO, vx0 = vp0 % HALO;
  const int gh0 = min(max(tileY*TILE + vy0 - RR, 0), NH-1);
  const int gw0 = min(max(tileX*TILE + vx0 - RR, 0), NW-1);
  const float* va0 = vis + ((size_t)(b*NPIX + gh0*NW + gw0))*ND + d0;
  const float* va1 = nullptr;
  int vy1 = 0, vx1 = 0;
  if (vp1 < NVIS) {
    vy1 = vp1 / HALO; vx1 = vp1 % HALO;
    const int gh1 = min(max(tileY*TILE + vy1 - RR, 0), NH-1);
    const int gw1 = min(max(tileX*TILE + vx1 - RR, 0), NW-1);
    va1 = vis + ((size_t)(b*NPIX + gh1*NW + gw1))*ND + d0;
  }
  float ssv0 = 0.f, ssv1 = 0.f;

  const float* ra = rubin + ((size_t)(b*NPIX + h*NW + w))*ND + d0;

  float acc[NK];
  #pragma unroll
  for (int j = 0; j < NK; ++j) acc[j] = 0.f;
  float ssr = 0.f;
  const int cbase = ((ty+RR)*HALO + (tx+RR))*LDST;

  for (int ch = 0; ch < nch; ++ch) {
    __syncthreads();   // protect previous iteration's readers
    {
      const float4* p0 = (const float4*)(va0 + ch*DC);
      float4* q0 = (float4*)&lds[vp0*LDST];
      #pragma unroll
      for (int q = 0; q < 4; ++q) {
        float4 v = p0[q];
        ssv0 += v.x*v.x + v.y*v.y + v.z*v.z + v.w*v.w;
        q0[q] = v;
      }
      if (va1) {
        const float4* p1 = (const float4*)(va1 + ch*DC);
        float4* q1 = (float4*)&lds[vp1*LDST];
        #pragma unroll
        for (int q = 0; q < 4; ++q) {
          float4 v = p1[q];
          ssv1 += v.x*v.x + v.y*v.y + v.z*v.z + v.w*v.w;
          q1[q] = v;
        }
      }
    }
    __syncthreads();

    float4 r[4];
    const float4* rp = (const float4*)(ra + ch*DC);
    #pragma unroll
    for (int q = 0; q < 4; ++q) {
      r[q] = rp[q];
      ssr += r[q].x*r[q].x + r[q].y*r[q].y + r[q].z*r[q].z + r[q].w*r[q].w;
    }
    #pragma unroll
    for (int jy = 0; jy < 7; ++jy) {
      #pragma unroll
      for (int jx = 0; jx < 7; ++jx) {
        const float* vptr = &lds[cbase + ((jy-RR)*HALO + (jx-RR))*LDST];
        float a = acc[jy*7+jx];
        #pragma unroll
        for (int q = 0; q < 4; ++q) {
          float4 v = *(const float4*)(vptr + q*4);
          a = fmaf(r[q].x, v.x, a);
          a = fmaf(r[q].y, v.y, a);
          a = fmaf(r[q].z, v.z, a);
          a = fmaf(r[q].w, v.w, a);
        }
        acc[jy*7+jx] = a;
      }
    }
  }

  float* pb = part + ((size_t)(ns*NB + b)*51)*NPIX;
  const int n = h*NW + w;
  #pragma unroll
  for (int j = 0; j < NK; ++j) pb[(size_t)j*NPIX + n] = acc[j];
  pb[(size_t)49*NPIX + n] = ssr;
  // vis sum-of-squares for this tile's core pixels (each written exactly once)
  if (vy0 >= RR && vy0 < HALO-RR && vx0 >= RR && vx0 < HALO-RR) {
    const int nn = (tileY*TILE + vy0 - RR)*NW + tileX*TILE + vx0 - RR;
    pb[(size_t)50*NPIX + nn] = ssv0;
  }
  if (va1 && vy1 >= RR && vy1 < HALO-RR && vx1 >= RR && vx1 < HALO-RR) {
    const int nn = (tileY*TILE + vy1 - RR)*NW + tileX*TILE + vx1 - RR;
    pb[(size_t)50*NPIX + nn] = ssv1;
  }
}

// ---------------- kernel C0: reduce sums of squares -> inverse norms ----------------
__global__ void norm_kernel(const float* __restrict__ part, float* __restrict__ invr,
                            float* __restrict__ invv, int NS) {
  const int g = blockIdx.x*256 + threadIdx.x;      // 0..NB*NPIX-1
  const int b = g / NPIX, n = g % NPIX;
  float sr = 0.f, sv = 0.f;
  for (int ns = 0; ns < NS; ++ns) {
    const float* pb = part + ((size_t)(ns*NB + b)*51)*NPIX;
    sr += pb[(size_t)49*NPIX + n];
    sv += pb[(size_t)50*NPIX + n];
  }
  invr[g] = 1.f / fmaxf(sqrtf(sr), 1e-6f);
  invv[g] = 1.f / fmaxf(sqrtf(sv), 1e-6f);
}

// ---------------- kernel C: logits + local softmax + global partials ----------------
__global__ __launch_bounds__(256) void local_kernel(
    const float* __restrict__ part, const float* __restrict__ invr,
    const float* __restrict__ invv, float* __restrict__ dyl, float* __restrict__ dxl,
    float* __restrict__ gacc, float* __restrict__ out, int NS) {
  const int g = blockIdx.x*256 + threadIdx.x;
  const int b = g / NPIX, n = g % NPIX;
  const int h = n / NW, w = n % NW;
  const float ir = invr[g] * (SCALE / TAU);   // fold scale and 1/TAU
  float t[NK];
  const float* pb0 = part + (size_t)b*51*NPIX + n;
  #pragma unroll
  for (int jy = 0; jy < 7; ++jy) {
    #pragma unroll
    for (int jx = 0; jx < 7; ++jx) {
      const int j = jy*7 + jx;
      float c = 0.f;
      for (int ns = 0; ns < NS; ++ns)
        c += pb0[((size_t)(ns*NB)*51 + j)*NPIX];
      const int hh = min(max(h + jy - RR, 0), NH-1);
      const int wc = min(max(w + jx - RR, 0), NW-1);
      t[j] = c * ir * invv[b*NPIX + hh*NW + wc];   // = logits/TAU
    }
  }
  // deterministic per-wave partial sums (for the global mean softmax)
  const int lane = threadIdx.x & 63;
  const int waveid = (blockIdx.x % 36)*4 + (threadIdx.x >> 6);   // 0..143 per b
  #pragma unroll
  for (int j = 0; j < NK; ++j) {
    float red = t[j];
    #pragma unroll
    for (int m = 1; m < 64; m <<= 1) red += __shfl_xor(red, m);
    if (lane == 0) gacc[((size_t)b*NK + j)*144 + waveid] = red;
  }
  // local softmax
  float mx = t[0];
  #pragma unroll
  for (int j = 1; j < NK; ++j) mx = fmaxf(mx, t[j]);
  float s = 0.f, sy = 0.f, sx = 0.f;
  #pragma unroll
  for (int jy = 0; jy < 7; ++jy) {
    #pragma unroll
    for (int jx = 0; jx < 7; ++jx) {
      const float e = expf(t[jy*7+jx] - mx);
      s += e; sy += e*(float)(jy-RR); sx += e*(float)(jx-RR);
    }
  }
  const float inv_s = 1.f / s;            // conf_local = max prob = exp(0)/s
  dyl[g] = sy * inv_s;
  dxl[g] = sx * inv_s;
  out[(size_t)2*NB*NPIX + g] = inv_s;     // conf_local
  const float lw = fminf(fmaxf((inv_s - UNI)/(1.f-UNI), 0.f), 1.f);
  out[(size_t)3*NB*NPIX + 4 + g] = lw;    // lw
}

// ---------------- kernel D: global softmax per batch ----------------
__global__ void global_kernel(const float* __restrict__ gacc, float* __restrict__ gres,
                              float* __restrict__ out) {
  const int b = blockIdx.x;
  const int k = threadIdx.x;   // 64 threads = 1 wave
  float t = -1e30f;
  if (k < NK) {
    float ssum = 0.f;
    for (int i = 0; i < 144; ++i) ssum += gacc[((size_t)b*NK + k)*144 + i];
    t = ssum * (1.f / (float)NPIX);
  }
  float m = t;
  #pragma unroll
  for (int msk = 1; msk < 64; msk <<= 1) m = fmaxf(m, __shfl_xor(m, msk));
  const float e = (k < NK) ? expf(t - m) : 0.f;
  const float dyv = (k < NK) ? (float)(k/7 - RR) : 0.f;
  const float dxv = (k < NK) ? (float)(k%7 - RR) : 0.f;
  float s = e, sy = e*dyv, sx = e*dxv;
  #pragma unroll
  for (int msk = 1; msk < 64; msk <<= 1) {
    s  += __shfl_xor(s,  msk);
    sy += __shfl_xor(sy, msk);
    sx += __shfl_xor(sx, msk);
  }
  if (k == 0) {
    out[(size_t)3*NB*NPIX + b] = 1.f / s;   // conf_global
    gres[b]     = sy / s;                   // dy_global
    gres[4 + b] = sx / s;                   // dx_global
  }
}

// ---------------- kernel E: blend + 3x3 zero-padded smooth + sky scale ----------------
__global__ __launch_bounds__(256) void smooth_kernel(
    const float* __restrict__ dyl, const float* __restrict__ dxl,
    const float* __restrict__ gres, float* __restrict__ out,
    const int* __restrict__ hvisp, const int* __restrict__ wvisp) {
  const int g = blockIdx.x*256 + threadIdx.x;
  const int b = g / NPIX, n = g % NPIX;
  const int h = n / NW, w = n % NW;
  const float dyg = gres[b], dxg = gres[4+b];
  const float* conf = out + (size_t)2*NB*NPIX;
  float sy = 0.f, sx = 0.f;
  #pragma unroll
  for (int ddy = -1; ddy <= 1; ++ddy) {
    #pragma unroll
    for (int ddx = -1; ddx <= 1; ++ddx) {
      const int hh = h + ddy, wc = w + ddx;
      if (hh >= 0 && hh < NH && wc >= 0 && wc < NW) {   // zero padding
        const int q = b*NPIX + hh*NW + wc;
        const float cf = conf[q];
        const float lw = fminf(fmaxf((cf - UNI)/(1.f-UNI), 0.f), 1.f);
        sy += lw*dyl[q] + (1.f-lw)*dyg;
        sx += lw*dxl[q] + (1.f-lw)*dxg;
      }
    }
  }
  const float skyy = (float)hvisp[0] * 0.1f / (float)NH;
  const float skyx = (float)wvisp[0] * 0.1f / (float)NW;
  out[g] = sx * (1.f/9.f) * skyx;                     // dra
  out[(size_t)NB*NPIX + g] = sy * (1.f/9.f) * skyy;   // ddec
}

// ---------------- host launch ----------------
extern "C" void kernel_launch(void* const* d_in, const int* in_sizes, int n_in,
                              void* d_out, int out_size, void* d_ws, size_t ws_size,
                              hipStream_t stream) {
  (void)in_sizes; (void)n_in; (void)out_size;
  const float* rubin = (const float*)d_in[0];
  const float* vis   = (const float*)d_in[1];
  const int* hvis = (const int*)d_in[4];
  const int* wvis = (const int*)d_in[5];
  float* out = (float*)d_out;
  float* ws  = (float*)d_ws;

  // D-split factor: 4 (576 blocks) if workspace permits, else 1.
  int NS = 4;
  const size_t need4 = ((size_t)4*NB*51*NPIX + (size_t)4*NB*NPIX + (size_t)NB*NK*144 + 8) * 4;
  if (ws_size < need4) NS = 1;
  const int DQ = ND / NS;

  float* part = ws;
  float* invr = part + (size_t)NS*NB*51*NPIX;
  float* invv = invr + (size_t)NB*NPIX;
  float* dyl  = invv + (size_t)NB*NPIX;
  float* dxl  = dyl  + (size_t)NB*NPIX;
  float* gacc = dxl  + (size_t)NB*NPIX;
  float* gres = gacc + (size_t)NB*NK*144;

  dim3 gB(36, NS, NB);
  corr_kernel<<<gB, 256, 0, stream>>>(rubin, vis, part, DQ);
  norm_kernel<<<dim3((NB*NPIX)/256), 256, 0, stream>>>(part, invr, invv, NS);
  local_kernel<<<dim3((NB*NPIX)/256), 256, 0, stream>>>(part, invr, invv, dyl, dxl, gacc, out, NS);
  global_kernel<<<dim3(NB), 64, 0, stream>>>(gacc, gres, out);
  smooth_kernel<<<dim3((NB*NPIX)/256), 256, 0, stream>>>(dyl, dxl, gres, out, hvis, wvis);
}

// Round 2
// 261.164 us; speedup vs baseline: 1.4206x; 1.4206x over previous
//
#include <hip/hip_runtime.h>
#include <math.h>

// ---------------- problem constants (from setup_inputs) ----------------
#define NB 4
#define NH 96
#define NW 96
#define ND 768
#define NPIX (NH*NW)          // 9216
#define RR 3
#define NK 49
#define TW 16                 // tile width (output pixels)
#define TH 16                 // tile height
#define HW_ 22                // halo width  (TW + 6)
#define HH_ 22                // halo height (TH + 6)
#define NVIS (HW_*HH_)        // 484
#define PAD 24                // padded LDS row stride (floats)
#define PS (HH_*PAD)          // LDS plane stride per d (528 floats)
#define DCC 16                // d-chunk staged in LDS per iteration
#define TAU 0.1f
#define SCALE 0.03608439182435161f  // 1/sqrt(768)
#define UNI (1.0f/49.0f)

// ws float layout:
//   part : [ns][b][51][NPIX]  (49 raw corr, 49: rubin_ss, 50: vis_ss)
//   invr : [b][NPIX]
//   invv : [b][NPIX]
//   dyl  : [b][NPIX]
//   dxl  : [b][NPIX]
//   gacc : [b][49][144]       per-wave partial sums of t=logits/TAU
//   gres : dyg[4], dxg[4]
// out float layout (flat concat, return order):
//   dra[36864] | ddec[36864] | conf_local[36864] | conf_global[4] | lw[36864]

// ---------------- kernel B: raw correlations + sums of squares ----------------
// d-major LDS, sliding-window taps, 2 output pixels per thread.
__global__ __launch_bounds__(128, 2) void corr_kernel(
    const float* __restrict__ rubin, const float* __restrict__ vis,
    float* __restrict__ part, int DQ) {
  __shared__ float lds[DCC * PS];   // 16*528*4 = 33,792 B
  const int tid = threadIdx.x;
  const int tileX = blockIdx.x % 6, tileY = blockIdx.x / 6;
  const int ns = blockIdx.y, b = blockIdx.z;
  const int xi = tid & 7, yi = tid >> 3;           // 8 x-threads, 16 y-rows
  const int x0 = tileX*TW + 2*xi, y = tileY*TH + yi;
  const int d0 = ns * DQ;
  const int nch = DQ / DCC;

  // staging setup: thread stages halo pixels tid, tid+128, tid+256, tid+384
  const float* vsrc0; const float* vsrc1; const float* vsrc2; const float* vsrc3;
  int svy0, svx0, svy1, svx1, svy2, svx2, svy3, svx3;
  {
    int sp, vy, vx, gh, gw;
    sp = tid;        vy = sp / HW_; vx = sp % HW_; svy0 = vy; svx0 = vx;
    gh = min(max(tileY*TH + vy - RR, 0), NH-1); gw = min(max(tileX*TW + vx - RR, 0), NW-1);
    vsrc0 = vis + ((size_t)(b*NPIX + gh*NW + gw))*ND + d0;
    sp = tid + 128;  vy = sp / HW_; vx = sp % HW_; svy1 = vy; svx1 = vx;
    gh = min(max(tileY*TH + vy - RR, 0), NH-1); gw = min(max(tileX*TW + vx - RR, 0), NW-1);
    vsrc1 = vis + ((size_t)(b*NPIX + gh*NW + gw))*ND + d0;
    sp = tid + 256;  vy = sp / HW_; vx = sp % HW_; svy2 = vy; svx2 = vx;
    gh = min(max(tileY*TH + vy - RR, 0), NH-1); gw = min(max(tileX*TW + vx - RR, 0), NW-1);
    vsrc2 = vis + ((size_t)(b*NPIX + gh*NW + gw))*ND + d0;
    sp = tid + 384;  // may be inactive (sp >= 484)
    vy = (sp < NVIS) ? sp / HW_ : 0; vx = (sp < NVIS) ? sp % HW_ : 0; svy3 = vy; svx3 = vx;
    gh = min(max(tileY*TH + vy - RR, 0), NH-1); gw = min(max(tileX*TW + vx - RR, 0), NW-1);
    vsrc3 = vis + ((size_t)(b*NPIX + gh*NW + gw))*ND + d0;
  }
  const bool act3 = (tid + 384) < NVIS;
  float ssv0 = 0.f, ssv1 = 0.f, ssv2 = 0.f, ssv3 = 0.f;

  const float* rsrc = rubin + ((size_t)(b*NPIX + y*NW + x0))*ND + d0;

  float acc[98];
  #pragma unroll
  for (int j = 0; j < 98; ++j) acc[j] = 0.f;
  float ssr0 = 0.f, ssr1 = 0.f;

  for (int ch = 0; ch < nch; ++ch) {
    // rubin loads issued early (no LDS dependence) — hidden under staging+barrier
    const float4* rp0 = (const float4*)(rsrc + (size_t)ch*DCC);
    const float4* rp1 = (const float4*)(rsrc + ND + (size_t)ch*DCC);
    float4 ra0 = rp0[0], ra1 = rp0[1], ra2 = rp0[2], ra3 = rp0[3];
    float4 rb0 = rp1[0], rb1 = rp1[1], rb2 = rp1[2], rb3 = rp1[3];

    if (ch) __syncthreads();   // previous chunk's readers done before overwrite

    // stage vis chunk into d-major LDS (scatter: 16 scalar writes per pixel)
    {
      const float4* vp = (const float4*)(vsrc0 + (size_t)ch*DCC);
      float4 v0 = vp[0], v1 = vp[1], v2 = vp[2], v3 = vp[3];
      ssv0 += v0.x*v0.x + v0.y*v0.y + v0.z*v0.z + v0.w*v0.w
            + v1.x*v1.x + v1.y*v1.y + v1.z*v1.z + v1.w*v1.w
            + v2.x*v2.x + v2.y*v2.y + v2.z*v2.z + v2.w*v2.w
            + v3.x*v3.x + v3.y*v3.y + v3.z*v3.z + v3.w*v3.w;
      const int a = svy0*PAD + svx0;
      lds[ 0*PS + a] = v0.x; lds[ 1*PS + a] = v0.y; lds[ 2*PS + a] = v0.z; lds[ 3*PS + a] = v0.w;
      lds[ 4*PS + a] = v1.x; lds[ 5*PS + a] = v1.y; lds[ 6*PS + a] = v1.z; lds[ 7*PS + a] = v1.w;
      lds[ 8*PS + a] = v2.x; lds[ 9*PS + a] = v2.y; lds[10*PS + a] = v2.z; lds[11*PS + a] = v2.w;
      lds[12*PS + a] = v3.x; lds[13*PS + a] = v3.y; lds[14*PS + a] = v3.z; lds[15*PS + a] = v3.w;
    }
    {
      const float4* vp = (const float4*)(vsrc1 + (size_t)ch*DCC);
      float4 v0 = vp[0], v1 = vp[1], v2 = vp[2], v3 = vp[3];
      ssv1 += v0.x*v0.x + v0.y*v0.y + v0.z*v0.z + v0.w*v0.w
            + v1.x*v1.x + v1.y*v1.y + v1.z*v1.z + v1.w*v1.w
            + v2.x*v2.x + v2.y*v2.y + v2.z*v2.z + v2.w*v2.w
            + v3.x*v3.x + v3.y*v3.y + v3.z*v3.z + v3.w*v3.w;
      const int a = svy1*PAD + svx1;
      lds[ 0*PS + a] = v0.x; lds[ 1*PS + a] = v0.y; lds[ 2*PS + a] = v0.z; lds[ 3*PS + a] = v0.w;
      lds[ 4*PS + a] = v1.x; lds[ 5*PS + a] = v1.y; lds[ 6*PS + a] = v1.z; lds[ 7*PS + a] = v1.w;
      lds[ 8*PS + a] = v2.x; lds[ 9*PS + a] = v2.y; lds[10*PS + a] = v2.z; lds[11*PS + a] = v2.w;
      lds[12*PS + a] = v3.x; lds[13*PS + a] = v3.y; lds[14*PS + a] = v3.z; lds[15*PS + a] = v3.w;
    }
    {
      const float4* vp = (const float4*)(vsrc2 + (size_t)ch*DCC);
      float4 v0 = vp[0], v1 = vp[1], v2 = vp[2], v3 = vp[3];
      ssv2 += v0.x*v0.x + v0.y*v0.y + v0.z*v0.z + v0.w*v0.w
            + v1.x*v1.x + v1.y*v1.y + v1.z*v1.z + v1.w*v1.w
            + v2.x*v2.x + v2.y*v2.y + v2.z*v2.z + v2.w*v2.w
            + v3.x*v3.x + v3.y*v3.y + v3.z*v3.z + v3.w*v3.w;
      const int a = svy2*PAD + svx2;
      lds[ 0*PS + a] = v0.x; lds[ 1*PS + a] = v0.y; lds[ 2*PS + a] = v0.z; lds[ 3*PS + a] = v0.w;
      lds[ 4*PS + a] = v1.x; lds[ 5*PS + a] = v1.y; lds[ 6*PS + a] = v1.z; lds[ 7*PS + a] = v1.w;
      lds[ 8*PS + a] = v2.x; lds[ 9*PS + a] = v2.y; lds[10*PS + a] = v2.z; lds[11*PS + a] = v2.w;
      lds[12*PS + a] = v3.x; lds[13*PS + a] = v3.y; lds[14*PS + a] = v3.z; lds[15*PS + a] = v3.w;
    }
    if (act3) {
      const float4* vp = (const float4*)(vsrc3 + (size_t)ch*DCC);
      float4 v0 = vp[0], v1 = vp[1], v2 = vp[2], v3 = vp[3];
      ssv3 += v0.x*v0.x + v0.y*v0.y + v0.z*v0.z + v0.w*v0.w
            + v1.x*v1.x + v1.y*v1.y + v1.z*v1.z + v1.w*v1.w
            + v2.x*v2.x + v2.y*v2.y + v2.z*v2.z + v2.w*v2.w
            + v3.x*v3.x + v3.y*v3.y + v3.z*v3.z + v3.w*v3.w;
      const int a = svy3*PAD + svx3;
      lds[ 0*PS + a] = v0.x; lds[ 1*PS + a] = v0.y; lds[ 2*PS + a] = v0.z; lds[ 3*PS + a] = v0.w;
      lds[ 4*PS + a] = v1.x; lds[ 5*PS + a] = v1.y; lds[ 6*PS + a] = v1.z; lds[ 7*PS + a] = v1.w;
      lds[ 8*PS + a] = v2.x; lds[ 9*PS + a] = v2.z; lds[10*PS + a] = v2.z; lds[11*PS + a] = v2.w;
      lds[12*PS + a] = v3.x; lds[13*PS + a] = v3.y; lds[14*PS + a] = v3.z; lds[15*PS + a] = v3.w;
      lds[ 9*PS + a] = v2.y;   // (explicit fix to keep mapping exact)
    }
    __syncthreads();

    ssr0 += ra0.x*ra0.x + ra0.y*ra0.y + ra0.z*ra0.z + ra0.w*ra0.w
          + ra1.x*ra1.x + ra1.y*ra1.y + ra1.z*ra1.z + ra1.w*ra1.w
          + ra2.x*ra2.x + ra2.y*ra2.y + ra2.z*ra2.z + ra2.w*ra2.w
          + ra3.x*ra3.x + ra3.y*ra3.y + ra3.z*ra3.z + ra3.w*ra3.w;
    ssr1 += rb0.x*rb0.x + rb0.y*rb0.y + rb0.z*rb0.z + rb0.w*rb0.w
          + rb1.x*rb1.x + rb1.y*rb1.y + rb1.z*rb1.z + rb1.w*rb1.w
          + rb2.x*rb2.x + rb2.y*rb2.y + rb2.z*rb2.z + rb2.w*rb2.w
          + rb3.x*rb3.x + rb3.y*rb3.y + rb3.z*rb3.z + rb3.w*rb3.w;

    const float rr0[16] = {ra0.x,ra0.y,ra0.z,ra0.w, ra1.x,ra1.y,ra1.z,ra1.w,
                           ra2.x,ra2.y,ra2.z,ra2.w, ra3.x,ra3.y,ra3.z,ra3.w};
    const float rr1[16] = {rb0.x,rb0.y,rb0.z,rb0.w, rb1.x,rb1.y,rb1.z,rb1.w,
                           rb2.x,rb2.y,rb2.z,rb2.w, rb3.x,rb3.y,rb3.z,rb3.w};
    #pragma unroll
    for (int dd = 0; dd < DCC; ++dd) {
      const float r0 = rr0[dd], r1 = rr1[dd];
      #pragma unroll
      for (int jy = 0; jy < 7; ++jy) {
        const float* p = &lds[dd*PS + (yi+jy)*PAD + 2*xi];   // cols 2xi..2xi+7, 8B-aligned
        const float2 w0 = *(const float2*)(p);
        const float2 w1 = *(const float2*)(p+2);
        const float2 w2 = *(const float2*)(p+4);
        const float2 w3 = *(const float2*)(p+6);
        const float w[8] = {w0.x,w0.y,w1.x,w1.y,w2.x,w2.y,w3.x,w3.y};
        #pragma unroll
        for (int jx = 0; jx < 7; ++jx) {
          acc[jy*7+jx]    = fmaf(r0, w[jx],   acc[jy*7+jx]);
          acc[49+jy*7+jx] = fmaf(r1, w[jx+1], acc[49+jy*7+jx]);
        }
      }
    }
  }

  float* pb = part + ((size_t)(ns*NB + b)*51)*NPIX;
  const int n = y*NW + x0;
  #pragma unroll
  for (int j = 0; j < NK; ++j) {
    pb[(size_t)j*NPIX + n]     = acc[j];
    pb[(size_t)j*NPIX + n + 1] = acc[49+j];
  }
  pb[(size_t)49*NPIX + n]     = ssr0;
  pb[(size_t)49*NPIX + n + 1] = ssr1;
  // vis sum-of-squares for this tile's core pixels (each staged exactly once)
  if (svy0 >= RR && svy0 < HH_-RR && svx0 >= RR && svx0 < HW_-RR) {
    const int nn = (tileY*TH + svy0 - RR)*NW + tileX*TW + svx0 - RR;
    pb[(size_t)50*NPIX + nn] = ssv0;
  }
  if (svy1 >= RR && svy1 < HH_-RR && svx1 >= RR && svx1 < HW_-RR) {
    const int nn = (tileY*TH + svy1 - RR)*NW + tileX*TW + svx1 - RR;
    pb[(size_t)50*NPIX + nn] = ssv1;
  }
  if (svy2 >= RR && svy2 < HH_-RR && svx2 >= RR && svx2 < HW_-RR) {
    const int nn = (tileY*TH + svy2 - RR)*NW + tileX*TW + svx2 - RR;
    pb[(size_t)50*NPIX + nn] = ssv2;
  }
  if (act3 && svy3 >= RR && svy3 < HH_-RR && svx3 >= RR && svx3 < HW_-RR) {
    const int nn = (tileY*TH + svy3 - RR)*NW + tileX*TW + svx3 - RR;
    pb[(size_t)50*NPIX + nn] = ssv3;
  }
}

// ---------------- kernel C0: reduce sums of squares -> inverse norms ----------------
__global__ void norm_kernel(const float* __restrict__ part, float* __restrict__ invr,
                            float* __restrict__ invv, int NS) {
  const int g = blockIdx.x*256 + threadIdx.x;      // 0..NB*NPIX-1
  const int b = g / NPIX, n = g % NPIX;
  float sr = 0.f, sv = 0.f;
  for (int ns = 0; ns < NS; ++ns) {
    const float* pb = part + ((size_t)(ns*NB + b)*51)*NPIX;
    sr += pb[(size_t)49*NPIX + n];
    sv += pb[(size_t)50*NPIX + n];
  }
  invr[g] = 1.f / fmaxf(sqrtf(sr), 1e-6f);
  invv[g] = 1.f / fmaxf(sqrtf(sv), 1e-6f);
}

// ---------------- kernel C: logits + local softmax + global partials ----------------
__global__ __launch_bounds__(256) void local_kernel(
    const float* __restrict__ part, const float* __restrict__ invr,
    const float* __restrict__ invv, float* __restrict__ dyl, float* __restrict__ dxl,
    float* __restrict__ gacc, float* __restrict__ out, int NS) {
  const int g = blockIdx.x*256 + threadIdx.x;
  const int b = g / NPIX, n = g % NPIX;
  const int h = n / NW, w = n % NW;
  const float ir = invr[g] * (SCALE / TAU);   // fold scale and 1/TAU
  float t[NK];
  const float* pb0 = part + (size_t)b*51*NPIX + n;
  #pragma unroll
  for (int jy = 0; jy < 7; ++jy) {
    #pragma unroll
    for (int jx = 0; jx < 7; ++jx) {
      const int j = jy*7 + jx;
      float c = 0.f;
      for (int ns = 0; ns < NS; ++ns)
        c += pb0[((size_t)(ns*NB)*51 + j)*NPIX];
      const int hh = min(max(h + jy - RR, 0), NH-1);
      const int wc = min(max(w + jx - RR, 0), NW-1);
      t[j] = c * ir * invv[b*NPIX + hh*NW + wc];   // = logits/TAU
    }
  }
  // deterministic per-wave partial sums (for the global mean softmax)
  const int lane = threadIdx.x & 63;
  const int waveid = (blockIdx.x % 36)*4 + (threadIdx.x >> 6);   // 0..143 per b
  #pragma unroll
  for (int j = 0; j < NK; ++j) {
    float red = t[j];
    #pragma unroll
    for (int m = 1; m < 64; m <<= 1) red += __shfl_xor(red, m);
    if (lane == 0) gacc[((size_t)b*NK + j)*144 + waveid] = red;
  }
  // local softmax
  float mx = t[0];
  #pragma unroll
  for (int j = 1; j < NK; ++j) mx = fmaxf(mx, t[j]);
  float s = 0.f, sy = 0.f, sx = 0.f;
  #pragma unroll
  for (int jy = 0; jy < 7; ++jy) {
    #pragma unroll
    for (int jx = 0; jx < 7; ++jx) {
      const float e = expf(t[jy*7+jx] - mx);
      s += e; sy += e*(float)(jy-RR); sx += e*(float)(jx-RR);
    }
  }
  const float inv_s = 1.f / s;            // conf_local = max prob = exp(0)/s
  dyl[g] = sy * inv_s;
  dxl[g] = sx * inv_s;
  out[(size_t)2*NB*NPIX + g] = inv_s;     // conf_local
  const float lw = fminf(fmaxf((inv_s - UNI)/(1.f-UNI), 0.f), 1.f);
  out[(size_t)3*NB*NPIX + 4 + g] = lw;    // lw
}

// ---------------- kernel D: global softmax per batch ----------------
__global__ void global_kernel(const float* __restrict__ gacc, float* __restrict__ gres,
                              float* __restrict__ out) {
  const int b = blockIdx.x;
  const int k = threadIdx.x;   // 64 threads = 1 wave
  float t = -1e30f;
  if (k < NK) {
    float ssum = 0.f;
    for (int i = 0; i < 144; ++i) ssum += gacc[((size_t)b*NK + k)*144 + i];
    t = ssum * (1.f / (float)NPIX);
  }
  float m = t;
  #pragma unroll
  for (int msk = 1; msk < 64; msk <<= 1) m = fmaxf(m, __shfl_xor(m, msk));
  const float e = (k < NK) ? expf(t - m) : 0.f;
  const float dyv = (k < NK) ? (float)(k/7 - RR) : 0.f;
  const float dxv = (k < NK) ? (float)(k%7 - RR) : 0.f;
  float s = e, sy = e*dyv, sx = e*dxv;
  #pragma unroll
  for (int msk = 1; msk < 64; msk <<= 1) {
    s  += __shfl_xor(s,  msk);
    sy += __shfl_xor(sy, msk);
    sx += __shfl_xor(sx, msk);
  }
  if (k == 0) {
    out[(size_t)3*NB*NPIX + b] = 1.f / s;   // conf_global
    gres[b]     = sy / s;                   // dy_global
    gres[4 + b] = sx / s;                   // dx_global
  }
}

// ---------------- kernel E: blend + 3x3 zero-padded smooth + sky scale ----------------
__global__ __launch_bounds__(256) void smooth_kernel(
    const float* __restrict__ dyl, const float* __restrict__ dxl,
    const float* __restrict__ gres, float* __restrict__ out,
    const int* __restrict__ hvisp, const int* __restrict__ wvisp) {
  const int g = blockIdx.x*256 + threadIdx.x;
  const int b = g / NPIX, n = g % NPIX;
  const int h = n / NW, w = n % NW;
  const float dyg = gres[b], dxg = gres[4+b];
  const float* conf = out + (size_t)2*NB*NPIX;
  float sy = 0.f, sx = 0.f;
  #pragma unroll
  for (int ddy = -1; ddy <= 1; ++ddy) {
    #pragma unroll
    for (int ddx = -1; ddx <= 1; ++ddx) {
      const int hh = h + ddy, wc = w + ddx;
      if (hh >= 0 && hh < NH && wc >= 0 && wc < NW) {   // zero padding
        const int q = b*NPIX + hh*NW + wc;
        const float cf = conf[q];
        const float lw = fminf(fmaxf((cf - UNI)/(1.f-UNI), 0.f), 1.f);
        sy += lw*dyl[q] + (1.f-lw)*dyg;
        sx += lw*dxl[q] + (1.f-lw)*dxg;
      }
    }
  }
  const float skyy = (float)hvisp[0] * 0.1f / (float)NH;
  const float skyx = (float)wvisp[0] * 0.1f / (float)NW;
  out[g] = sx * (1.f/9.f) * skyx;                     // dra
  out[(size_t)NB*NPIX + g] = sy * (1.f/9.f) * skyy;   // ddec
}

// ---------------- host launch ----------------
extern "C" void kernel_launch(void* const* d_in, const int* in_sizes, int n_in,
                              void* d_out, int out_size, void* d_ws, size_t ws_size,
                              hipStream_t stream) {
  (void)in_sizes; (void)n_in; (void)out_size;
  const float* rubin = (const float*)d_in[0];
  const float* vis   = (const float*)d_in[1];
  const int* hvis = (const int*)d_in[4];
  const int* wvis = (const int*)d_in[5];
  float* out = (float*)d_out;
  float* ws  = (float*)d_ws;

  // D-split factor: 4 (576 blocks) if workspace permits, else 1.
  int NS = 4;
  const size_t need4 = ((size_t)4*NB*51*NPIX + (size_t)4*NB*NPIX + (size_t)NB*NK*144 + 8) * 4;
  if (ws_size < need4) NS = 1;
  const int DQ = ND / NS;

  float* part = ws;
  float* invr = part + (size_t)NS*NB*51*NPIX;
  float* invv = invr + (size_t)NB*NPIX;
  float* dyl  = invv + (size_t)NB*NPIX;
  float* dxl  = dyl  + (size_t)NB*NPIX;
  float* gacc = dxl  + (size_t)NB*NPIX;
  float* gres = gacc + (size_t)NB*NK*144;

  dim3 gB(36, NS, NB);
  corr_kernel<<<gB, 128, 0, stream>>>(rubin, vis, part, DQ);
  norm_kernel<<<dim3((NB*NPIX)/256), 256, 0, stream>>>(part, invr, invv, NS);
  local_kernel<<<dim3((NB*NPIX)/256), 256, 0, stream>>>(part, invr, invv, dyl, dxl, gacc, out, NS);
  global_kernel<<<dim3(NB), 64, 0, stream>>>(gacc, gres, out);
  smooth_kernel<<<dim3((NB*NPIX)/256), 256, 0, stream>>>(dyl, dxl, gres, out, hvis, wvis);
}

// Round 3
// 129.413 us; speedup vs baseline: 2.8668x; 2.0181x over previous
//
#include <hip/hip_runtime.h>
#include <math.h>

// ---------------- problem constants ----------------
#define NB 4
#define NH 96
#define NW 96
#define ND 768
#define NPIX (NH*NW)          // 9216
#define RR 3
#define NK 49
#define NS 4                  // D-split: 4 x 192
#define KQ 192                // K per split
#define NCH 6                 // chunks of 32 per split
#define TS 16                 // tile 16x16 pixels
#define HL 22                 // halo 22x22
#define LROW 40               // LDS ushorts per pixel row (32 data + 8 pad = 80B)
#define TAU 0.1f
#define SCALE 0.03608439182435161f  // 1/sqrt(768)
#define UNI (1.0f/49.0f)

typedef float f32x4 __attribute__((ext_vector_type(4)));
typedef short bfx8 __attribute__((ext_vector_type(8)));

// ws layout:
//   partL : ushort [ns][b][49][NPIX]   raw bf16 corr partials
//   partS : float  [ns][b][2][NPIX]    (0: rubin ss, 1: vis ss)
//   invr, invv, dyl, dxl : float [b][NPIX]
//   gacc : float [b][49][144]
//   gres : float dyg[4], dxg[4]
// out: dra[36864] | ddec[36864] | conf_local[36864] | conf_global[4] | lw[36864]

__device__ __forceinline__ unsigned bfpk(float lo, float hi) {
  unsigned a = __builtin_bit_cast(unsigned, lo);
  unsigned b = __builtin_bit_cast(unsigned, hi);
  a = (a + 0x7fffu + ((a >> 16) & 1u)) >> 16;          // RNE low half
  b = (b + 0x7fffu + ((b >> 16) & 1u)) & 0xffff0000u;  // RNE high half
  return a | b;
}
__device__ __forceinline__ unsigned short bf1(float v) {
  unsigned a = __builtin_bit_cast(unsigned, v);
  return (unsigned short)((a + 0x7fffu + ((a >> 16) & 1u)) >> 16);
}

// stage 32 fp32 -> 32 bf16 into LDS (4x ds_write_b128), accumulate sum-of-squares
__device__ __forceinline__ void stage32(const float* __restrict__ src,
                                        unsigned short* lp, float& ss) {
  const float4* p = (const float4*)src;
  uint4* q = (uint4*)lp;
  #pragma unroll
  for (int u = 0; u < 4; ++u) {
    float4 v0 = p[2*u], v1 = p[2*u+1];
    ss += v0.x*v0.x + v0.y*v0.y + v0.z*v0.z + v0.w*v0.w
        + v1.x*v1.x + v1.y*v1.y + v1.z*v1.z + v1.w*v1.w;
    q[u] = make_uint4(bfpk(v0.x,v0.y), bfpk(v0.z,v0.w),
                      bfpk(v1.x,v1.y), bfpk(v1.z,v1.w));
  }
}

// ---------------- kernel B: banded MFMA correlation ----------------
__global__ __launch_bounds__(512, 2) void corr_kernel(
    const float* __restrict__ rubin, const float* __restrict__ vis,
    unsigned short* __restrict__ partL, float* __restrict__ partS) {
  __shared__ __align__(16) unsigned short ldsA[TS*TS*LROW];  // 20,480 B
  __shared__ __align__(16) unsigned short ldsB[HL*HL*LROW];  // 38,720 B
  const int tid = threadIdx.x;
  const int tileX = blockIdx.x % 6, tileY = blockIdx.x / 6;
  const int ns = blockIdx.y, b = blockIdx.z;
  const int k0 = ns * KQ;

  // ---- staging slot assignment: slots 0..483 vis-halo, 484..739 rubin ----
  const float* srcA; unsigned short* ldpA; int ssPixA = -1, ssPlaneA = 0;
  {
    const int s = tid;
    if (s < 484) {
      const int vy = s / HL, vx = s % HL;
      const int gh = min(max(tileY*TS + vy - RR, 0), NH-1);
      const int gw = min(max(tileX*TS + vx - RR, 0), NW-1);
      srcA = vis + ((size_t)(b*NPIX + gh*NW + gw))*ND + k0;
      ldpA = ldsB + s*LROW;
      if (vy >= RR && vy < HL-RR && vx >= RR && vx < HL-RR) {
        ssPixA = (tileY*TS + vy - RR)*NW + tileX*TS + vx - RR; ssPlaneA = 1;
      }
    } else {
      const int ridx = s - 484, yi = ridx / TS, xi = ridx % TS;
      srcA = rubin + ((size_t)(b*NPIX + (tileY*TS+yi)*NW + tileX*TS+xi))*ND + k0;
      ldpA = ldsA + ridx*LROW;
      ssPixA = (tileY*TS+yi)*NW + tileX*TS+xi; ssPlaneA = 0;
    }
  }
  const float* srcB = rubin; unsigned short* ldpB = ldsA; int ssPixB = -1, ssPlaneB = 0;
  const bool actB = (tid + 512) < 740;
  if (actB) {
    const int s = tid + 512;
    if (s < 484) {
      const int vy = s / HL, vx = s % HL;
      const int gh = min(max(tileY*TS + vy - RR, 0), NH-1);
      const int gw = min(max(tileX*TS + vx - RR, 0), NW-1);
      srcB = vis + ((size_t)(b*NPIX + gh*NW + gw))*ND + k0;
      ldpB = ldsB + s*LROW;
      if (vy >= RR && vy < HL-RR && vx >= RR && vx < HL-RR) {
        ssPixB = (tileY*TS + vy - RR)*NW + tileX*TS + vx - RR; ssPlaneB = 1;
      }
    } else {
      const int ridx = s - 484, yi = ridx / TS, xi = ridx % TS;
      srcB = rubin + ((size_t)(b*NPIX + (tileY*TS+yi)*NW + tileX*TS+xi))*ND + k0;
      ldpB = ldsA + ridx*LROW;
      ssPixB = (tileY*TS+yi)*NW + tileX*TS+xi; ssPlaneB = 0;
    }
  }
  float ssA = 0.f, ssB = 0.f;

  // ---- MFMA setup ----
  const int lane = tid & 63, wv = tid >> 6;
  const int y0 = wv*2;                  // wave owns tile rows y0, y0+1
  const int j = lane & 15, kq = lane >> 4;
  const int aOff0 = (y0*TS + j)*LROW + kq*8;       // A-frag: row=x-pixel j
  const int aOff1 = aOff0 + TS*LROW;
  const int bCol0 = j;                              // h=0 columns 0..15
  const int bCol1 = min(j + 16, HL-1);              // h=1 columns 16..21 (clamped)
  const int bOff0 = bCol0*LROW + kq*8;
  const int bOff1 = bCol1*LROW + kq*8;

  f32x4 acc[2][7][2];
  #pragma unroll
  for (int a0 = 0; a0 < 2; ++a0)
    #pragma unroll
    for (int a1 = 0; a1 < 7; ++a1)
      #pragma unroll
      for (int a2 = 0; a2 < 2; ++a2)
        acc[a0][a1][a2] = (f32x4){0.f, 0.f, 0.f, 0.f};

  for (int ch = 0; ch < NCH; ++ch) {
    if (ch) __syncthreads();                 // readers of prev chunk done
    stage32(srcA + ch*32, ldpA, ssA);
    if (actB) stage32(srcB + ch*32, ldpB, ssB);
    __syncthreads();

    const bfx8 A0 = *(const bfx8*)&ldsA[aOff0];
    const bfx8 A1 = *(const bfx8*)&ldsA[aOff1];
    bfx8 Bp0 = *(const bfx8*)&ldsB[y0*HL*LROW + bOff0];
    bfx8 Bp1 = *(const bfx8*)&ldsB[y0*HL*LROW + bOff1];
    #pragma unroll
    for (int dy = 0; dy < 7; ++dy) {
      const int rn = (y0 + dy + 1)*HL*LROW;
      const bfx8 Bc0 = *(const bfx8*)&ldsB[rn + bOff0];
      const bfx8 Bc1 = *(const bfx8*)&ldsB[rn + bOff1];
      acc[0][dy][0] = __builtin_amdgcn_mfma_f32_16x16x32_bf16(A0, Bp0, acc[0][dy][0], 0, 0, 0);
      acc[0][dy][1] = __builtin_amdgcn_mfma_f32_16x16x32_bf16(A0, Bp1, acc[0][dy][1], 0, 0, 0);
      acc[1][dy][0] = __builtin_amdgcn_mfma_f32_16x16x32_bf16(A1, Bc0, acc[1][dy][0], 0, 0, 0);
      acc[1][dy][1] = __builtin_amdgcn_mfma_f32_16x16x32_bf16(A1, Bc1, acc[1][dy][1], 0, 0, 0);
      Bp0 = Bc0; Bp1 = Bc1;
    }
  }

  // ---- epilogue: scatter valid band entries as bf16 ----
  unsigned short* pL = partL + ((size_t)(ns*NB + b)*NK)*NPIX;
  const int px0 = tileX*TS;
  #pragma unroll
  for (int yy = 0; yy < 2; ++yy) {
    const int py = tileY*TS + y0 + yy;
    #pragma unroll
    for (int dy = 0; dy < 7; ++dy)
      #pragma unroll
      for (int h = 0; h < 2; ++h)
        #pragma unroll
        for (int r = 0; r < 4; ++r) {
          const int i = kq*4 + r;                   // C row = (lane>>4)*4 + reg
          const int dxp3 = h ? (j + 16 - i) : (j - i);
          if (dxp3 >= 0 && dxp3 < 7)
            pL[(size_t)(dy*7 + dxp3)*NPIX + py*NW + px0 + i] = bf1(acc[yy][dy][h][r]);
        }
  }
  float* pS = partS + ((size_t)(ns*NB + b)*2)*NPIX;
  if (ssPixA >= 0) pS[(size_t)ssPlaneA*NPIX + ssPixA] = ssA;
  if (actB && ssPixB >= 0) pS[(size_t)ssPlaneB*NPIX + ssPixB] = ssB;
}

// ---------------- kernel C0: reduce ss -> inverse norms ----------------
__global__ void norm_kernel(const float* __restrict__ partS, float* __restrict__ invr,
                            float* __restrict__ invv) {
  const int g = blockIdx.x*256 + threadIdx.x;
  const int b = g / NPIX, n = g % NPIX;
  float sr = 0.f, sv = 0.f;
  #pragma unroll
  for (int ns = 0; ns < NS; ++ns) {
    sr += partS[((size_t)(ns*NB + b)*2 + 0)*NPIX + n];
    sv += partS[((size_t)(ns*NB + b)*2 + 1)*NPIX + n];
  }
  invr[g] = 1.f / fmaxf(sqrtf(sr), 1e-6f);
  invv[g] = 1.f / fmaxf(sqrtf(sv), 1e-6f);
}

// ---------------- kernel C: logits + local softmax + global partials ----------------
__global__ __launch_bounds__(256) void local_kernel(
    const unsigned short* __restrict__ partL, const float* __restrict__ invr,
    const float* __restrict__ invv, float* __restrict__ dyl, float* __restrict__ dxl,
    float* __restrict__ gacc, float* __restrict__ out) {
  const int g = blockIdx.x*256 + threadIdx.x;
  const int b = g / NPIX, n = g % NPIX;
  const int h = n / NW, w = n % NW;
  const float ir = invr[g] * (SCALE / TAU);
  float t[NK];
  #pragma unroll
  for (int jy = 0; jy < 7; ++jy) {
    #pragma unroll
    for (int jx = 0; jx < 7; ++jx) {
      const int j = jy*7 + jx;
      float c = 0.f;
      #pragma unroll
      for (int ns = 0; ns < NS; ++ns) {
        const unsigned u = partL[((size_t)(ns*NB + b)*NK + j)*NPIX + n];
        c += __builtin_bit_cast(float, u << 16);
      }
      const int hh = min(max(h + jy - RR, 0), NH-1);
      const int wc = min(max(w + jx - RR, 0), NW-1);
      t[j] = c * ir * invv[b*NPIX + hh*NW + wc];
    }
  }
  const int lane = threadIdx.x & 63;
  const int waveid = (blockIdx.x % 36)*4 + (threadIdx.x >> 6);
  #pragma unroll
  for (int j = 0; j < NK; ++j) {
    float red = t[j];
    #pragma unroll
    for (int m = 1; m < 64; m <<= 1) red += __shfl_xor(red, m);
    if (lane == 0) gacc[((size_t)b*NK + j)*144 + waveid] = red;
  }
  float mx = t[0];
  #pragma unroll
  for (int j = 1; j < NK; ++j) mx = fmaxf(mx, t[j]);
  float s = 0.f, sy = 0.f, sx = 0.f;
  #pragma unroll
  for (int jy = 0; jy < 7; ++jy)
    #pragma unroll
    for (int jx = 0; jx < 7; ++jx) {
      const float e = expf(t[jy*7+jx] - mx);
      s += e; sy += e*(float)(jy-RR); sx += e*(float)(jx-RR);
    }
  const float inv_s = 1.f / s;
  dyl[g] = sy * inv_s;
  dxl[g] = sx * inv_s;
  out[(size_t)2*NB*NPIX + g] = inv_s;
  const float lw = fminf(fmaxf((inv_s - UNI)/(1.f-UNI), 0.f), 1.f);
  out[(size_t)3*NB*NPIX + 4 + g] = lw;
}

// ---------------- kernel D: global softmax per batch ----------------
__global__ void global_kernel(const float* __restrict__ gacc, float* __restrict__ gres,
                              float* __restrict__ out) {
  const int b = blockIdx.x;
  const int k = threadIdx.x;
  float t = -1e30f;
  if (k < NK) {
    float ssum = 0.f;
    for (int i = 0; i < 144; ++i) ssum += gacc[((size_t)b*NK + k)*144 + i];
    t = ssum * (1.f / (float)NPIX);
  }
  float m = t;
  #pragma unroll
  for (int msk = 1; msk < 64; msk <<= 1) m = fmaxf(m, __shfl_xor(m, msk));
  const float e = (k < NK) ? expf(t - m) : 0.f;
  const float dyv = (k < NK) ? (float)(k/7 - RR) : 0.f;
  const float dxv = (k < NK) ? (float)(k%7 - RR) : 0.f;
  float s = e, sy = e*dyv, sx = e*dxv;
  #pragma unroll
  for (int msk = 1; msk < 64; msk <<= 1) {
    s  += __shfl_xor(s,  msk);
    sy += __shfl_xor(sy, msk);
    sx += __shfl_xor(sx, msk);
  }
  if (k == 0) {
    out[(size_t)3*NB*NPIX + b] = 1.f / s;
    gres[b]     = sy / s;
    gres[4 + b] = sx / s;
  }
}

// ---------------- kernel E: blend + 3x3 zero-padded smooth ----------------
__global__ __launch_bounds__(256) void smooth_kernel(
    const float* __restrict__ dyl, const float* __restrict__ dxl,
    const float* __restrict__ gres, float* __restrict__ out,
    const int* __restrict__ hvisp, const int* __restrict__ wvisp) {
  const int g = blockIdx.x*256 + threadIdx.x;
  const int b = g / NPIX, n = g % NPIX;
  const int h = n / NW, w = n % NW;
  const float dyg = gres[b], dxg = gres[4+b];
  const float* conf = out + (size_t)2*NB*NPIX;
  float sy = 0.f, sx = 0.f;
  #pragma unroll
  for (int ddy = -1; ddy <= 1; ++ddy)
    #pragma unroll
    for (int ddx = -1; ddx <= 1; ++ddx) {
      const int hh = h + ddy, wc = w + ddx;
      if (hh >= 0 && hh < NH && wc >= 0 && wc < NW) {
        const int q = b*NPIX + hh*NW + wc;
        const float cf = conf[q];
        const float lw = fminf(fmaxf((cf - UNI)/(1.f-UNI), 0.f), 1.f);
        sy += lw*dyl[q] + (1.f-lw)*dyg;
        sx += lw*dxl[q] + (1.f-lw)*dxg;
      }
    }
  const float skyy = (float)hvisp[0] * 0.1f / (float)NH;
  const float skyx = (float)wvisp[0] * 0.1f / (float)NW;
  out[g] = sx * (1.f/9.f) * skyx;
  out[(size_t)NB*NPIX + g] = sy * (1.f/9.f) * skyy;
}

// ---------------- host launch ----------------
extern "C" void kernel_launch(void* const* d_in, const int* in_sizes, int n_in,
                              void* d_out, int out_size, void* d_ws, size_t ws_size,
                              hipStream_t stream) {
  (void)in_sizes; (void)n_in; (void)out_size; (void)ws_size;
  const float* rubin = (const float*)d_in[0];
  const float* vis   = (const float*)d_in[1];
  const int* hvis = (const int*)d_in[4];
  const int* wvis = (const int*)d_in[5];
  float* out = (float*)d_out;

  unsigned short* partL = (unsigned short*)d_ws;                 // NS*NB*49*NPIX ushort
  float* partS = (float*)(partL + (size_t)NS*NB*NK*NPIX);        // NS*NB*2*NPIX f32
  float* invr = partS + (size_t)NS*NB*2*NPIX;
  float* invv = invr + (size_t)NB*NPIX;
  float* dyl  = invv + (size_t)NB*NPIX;
  float* dxl  = dyl  + (size_t)NB*NPIX;
  float* gacc = dxl  + (size_t)NB*NPIX;
  float* gres = gacc + (size_t)NB*NK*144;

  corr_kernel<<<dim3(36, NS, NB), 512, 0, stream>>>(rubin, vis, partL, partS);
  norm_kernel<<<dim3((NB*NPIX)/256), 256, 0, stream>>>(partS, invr, invv);
  local_kernel<<<dim3((NB*NPIX)/256), 256, 0, stream>>>(partL, invr, invv, dyl, dxl, gacc, out);
  global_kernel<<<dim3(NB), 64, 0, stream>>>(gacc, gres, out);
  smooth_kernel<<<dim3((NB*NPIX)/256), 256, 0, stream>>>(dyl, dxl, gres, out, hvis, wvis);
}